// Round 3
// baseline (168.327 us; speedup 1.0000x reference)
//
#include <hip/hip_runtime.h>

#define B_    64
#define HW_   196
#define HWP_  224
#define D_    768
#define E_    256
#define C_    10
#define MP_   (B_*HWP_)   // 14336 padded rows
#define K3K_  (E_*D_)     // 196608 deep-K for final contraction
#define K3NB_ 384         // K-split blocks for k3 (512 k per block)

typedef __bf16 bf16x8 __attribute__((ext_vector_type(8)));
typedef __bf16 bf16x4 __attribute__((ext_vector_type(4)));
typedef float  f32x4  __attribute__((ext_vector_type(4)));

// async global->LDS, 16B per lane; LDS dest is wave-uniform base + lane*16
__device__ __forceinline__ void gld_lds16(const void* g, void* l) {
  __builtin_amdgcn_global_load_lds((const __attribute__((address_space(1))) void*)g,
                                   (__attribute__((address_space(3))) void*)l, 16, 0, 0);
}

// ---------------- K0x: fp32 x -> bf16 hi/lo, zero-padded [B][HWP][D] ----------------
__global__ __launch_bounds__(256) void k0_x(const float* __restrict__ x,
                                            __bf16* __restrict__ xhi,
                                            __bf16* __restrict__ xlo) {
  size_t i4 = ((size_t)blockIdx.x * 256 + threadIdx.x) * 4;
  int d  = (int)(i4 % D_);
  size_t row = i4 / D_;
  int hp = (int)(row % HWP_);
  int b  = (int)(row / HWP_);
  float4 v = make_float4(0.f, 0.f, 0.f, 0.f);
  if (hp < HW_) v = *(const float4*)&x[((size_t)b * HW_ + hp) * D_ + d];
  float vv[4] = {v.x, v.y, v.z, v.w};
  bf16x4 h, l;
#pragma unroll
  for (int j = 0; j < 4; j++) {
    __bf16 hj = (__bf16)vv[j];
    float r = vv[j] - (float)hj;
    h[j] = hj;
    l[j] = (__bf16)r;
  }
  *(bf16x4*)&xhi[i4] = h;
  *(bf16x4*)&xlo[i4] = l;
}

// ---------------- K0prep: merged {ag_w -> bf16 hi/lo} and {lm_w -> W2 permute} --------
__global__ __launch_bounds__(256) void k0_prep(const float* __restrict__ w,
                                               __bf16* __restrict__ whi,
                                               __bf16* __restrict__ wlo,
                                               const float* __restrict__ lmw,
                                               __bf16* __restrict__ w2) {
  int bid = blockIdx.x;
  if (bid < 192) {
    size_t i4 = ((size_t)bid * 256 + threadIdx.x) * 4;
    float4 v = *(const float4*)&w[i4];
    float vv[4] = {v.x, v.y, v.z, v.w};
    bf16x4 h, l;
#pragma unroll
    for (int j = 0; j < 4; j++) {
      __bf16 hj = (__bf16)vv[j];
      float r = vv[j] - (float)hj;
      h[j] = hj;
      l[j] = (__bf16)r;
    }
    *(bf16x4*)&whi[i4] = h;
    *(bf16x4*)&wlo[i4] = l;
  } else {
    size_t i4 = ((size_t)(bid - 192) * 256 + threadIdx.x) * 4;  // < 16*K3K_
    int c = (int)(i4 / K3K_);
    int rem = (int)(i4 - (size_t)c * K3K_);
    int e = rem / D_;
    int d = rem - e * D_;
    bf16x4 o;
    if (c < C_) {
      float4 v = *(const float4*)&lmw[((size_t)e * C_ + c) * D_ + d];
      o[0] = (__bf16)v.x; o[1] = (__bf16)v.y; o[2] = (__bf16)v.z; o[3] = (__bf16)v.w;
    } else {
      o[0] = o[1] = o[2] = o[3] = (__bf16)0.0f;
    }
    *(bf16x4*)&w2[i4] = o;
  }
}

// ---------------- K1: sign GEMM, 3-term split-bf16 MFMA ----------------
// R2 post-mortem: LDS-pipe-THROUGHPUT-bound (32x32 wave tile = 1KB LDS read/MFMA,
// +4cyc/read conflict tax at stride-32). Now: 128x128 block, 4 waves each 64x64
// (0.33KB read/MFMA) + XOR swizzle slot'=q^((row>>1)&3) applied BOTH sides:
// pre-swizzled per-lane GLOBAL source col for the DMA (LDS stays linear, rule #21)
// and the same involution on ds_read addresses -> 2-way banked (free).
__global__ __launch_bounds__(256) void k1_signs(const __bf16* __restrict__ xhi,
                                                const __bf16* __restrict__ xlo,
                                                const __bf16* __restrict__ whi,
                                                const __bf16* __restrict__ wlo,
                                                const float* __restrict__ bias,
                                                __bf16* __restrict__ st) {
  __shared__ __align__(16) __bf16 Ah[2][128 * 32];
  __shared__ __align__(16) __bf16 Al[2][128 * 32];
  __shared__ __align__(16) __bf16 Bh[2][128 * 32];
  __shared__ __align__(16) __bf16 Bl[2][128 * 32];
  const int m0 = blockIdx.x * 128;
  const int n0 = blockIdx.y * 128;
  const int tid = threadIdx.x;
  const int wave = tid >> 6, lane = tid & 63;
  const int wm = (wave & 1) * 64, wn = (wave >> 1) * 64;
  const int q = lane >> 4, l15 = lane & 15;
  // staging: wave stages rows [wave*32, wave*32+32) of each array, 2 chunks of 16
  const int r0 = wave * 32 + (lane >> 2);                 // chunk0 block-local row
  const int sc = ((lane & 3) ^ ((r0 >> 1) & 3)) * 8;      // swizzled src col (halves)
                                                          // (row+16 -> same swizzle)
  const int ld0 = wave * 32 * 32;                         // LDS elem base chunk0
  const int ld1 = ld0 + 16 * 32;
  const size_t offA = (size_t)(m0 + r0) * D_ + sc;        // xhi/xlo lane source
  const size_t offB = (size_t)(n0 + r0) * D_ + sc;        // whi/wlo lane source
  const size_t rstep = (size_t)16 * D_;
  f32x4 acc[4][4] = {};

#define K1_STAGE(buf, kk) do { \
    gld_lds16(&xhi[offA + (kk)],         &Ah[buf][ld0]); \
    gld_lds16(&xhi[offA + rstep + (kk)], &Ah[buf][ld1]); \
    gld_lds16(&xlo[offA + (kk)],         &Al[buf][ld0]); \
    gld_lds16(&xlo[offA + rstep + (kk)], &Al[buf][ld1]); \
    gld_lds16(&whi[offB + (kk)],         &Bh[buf][ld0]); \
    gld_lds16(&whi[offB + rstep + (kk)], &Bh[buf][ld1]); \
    gld_lds16(&wlo[offB + (kk)],         &Bl[buf][ld0]); \
    gld_lds16(&wlo[offB + rstep + (kk)], &Bl[buf][ld1]); \
  } while (0)

  K1_STAGE(0, 0);
  __syncthreads();

  int cur = 0;
  for (int k0 = 0; k0 < D_; k0 += 32) {
    if (k0 + 32 < D_) K1_STAGE(cur ^ 1, k0 + 32);
    bf16x8 ah[4], al[4], bh[4], bl[4];
#pragma unroll
    for (int t = 0; t < 4; t++) {
      int ra = wm + t * 16 + l15;
      int rb = wn + t * 16 + l15;
      int sa = (q ^ ((ra >> 1) & 3)) * 8;
      int sb = (q ^ ((rb >> 1) & 3)) * 8;
      ah[t] = *(const bf16x8*)&Ah[cur][ra * 32 + sa];
      al[t] = *(const bf16x8*)&Al[cur][ra * 32 + sa];
      bh[t] = *(const bf16x8*)&Bh[cur][rb * 32 + sb];
      bl[t] = *(const bf16x8*)&Bl[cur][rb * 32 + sb];
    }
#pragma unroll
    for (int mt = 0; mt < 4; mt++)
#pragma unroll
      for (int nt = 0; nt < 4; nt++) {
        acc[mt][nt] = __builtin_amdgcn_mfma_f32_16x16x32_bf16(ah[mt], bh[nt], acc[mt][nt], 0, 0, 0);
        acc[mt][nt] = __builtin_amdgcn_mfma_f32_16x16x32_bf16(al[mt], bh[nt], acc[mt][nt], 0, 0, 0);
        acc[mt][nt] = __builtin_amdgcn_mfma_f32_16x16x32_bf16(ah[mt], bl[nt], acc[mt][nt], 0, 0, 0);
      }
    __syncthreads();
    cur ^= 1;
  }
#undef K1_STAGE

#pragma unroll
  for (int mt = 0; mt < 4; mt++)
#pragma unroll
    for (int nt = 0; nt < 4; nt++) {
      int e = n0 + wn + nt * 16 + l15;
      float bv = bias[e];
#pragma unroll
      for (int r = 0; r < 4; r++) {
        int m = m0 + wm + mt * 16 + q * 4 + r;   // C/D: row=quad*4+reg, col=lane&15
        int b = m / HWP_;
        int hp = m - b * HWP_;
        float v = acc[mt][nt][r] + bv;
        __bf16 s = (hp < HW_ && v > 0.0f) ? (__bf16)1.0f : (__bf16)0.0f;
        st[((size_t)b * E_ + e) * HWP_ + hp] = s;
      }
    }
}

// ---------------- K2: per-batch G = S^T · X  (M=256 e, N=768 d, K=224 hp) ----------------
// 2-phase prefetch (R2) + As now source-swizzled like k1 (conflict-free reads).
// Bs (transposed-on-stage, stride 40) kept: reads enumerate to 2-way, writes <=4-way.
__global__ __launch_bounds__(256) void k2_g(const __bf16* __restrict__ st,
                                            const __bf16* __restrict__ xhi,
                                            __bf16* __restrict__ g) {
  __shared__ __align__(16) __bf16 As[2][128 * 32];
  __shared__ __align__(16) __bf16 Bs[2][128 * 40];   // Bs[d][k], stride 40
  const int b  = blockIdx.y;
  const int e0 = (blockIdx.x / 6) * 128;
  const int d0 = (blockIdx.x % 6) * 128;
  const int tid = threadIdx.x;
  const int wave = tid >> 6, lane = tid & 63;
  const int wm = (wave & 1) * 64, wn = (wave >> 1) * 64;
  const int q = lane >> 4, l15 = lane & 15;
  const int sr = tid >> 2;                                 // As row 0..63 (chunk0)
  const int scA = ((lane & 3) ^ ((sr >> 1) & 3)) * 8;      // swizzled src col
  const int ldsoff = wave * 512;
  // Bs staging: thread owns 4k x 4d micro-tile -> 4x ds_write_b64
  const int kk4 = ((tid >> 2) & 7) * 4;                    // k offset 0..28
  const int dgroup = (tid & 3) | (((tid >> 5) & 7) << 2);  // 0..31
  const int dc0 = dgroup * 4;                              // d offset 0..124
  f32x4 acc[4][4] = {};

  const __bf16* gA0 = &st[((size_t)b * E_ + e0 + sr) * HWP_ + scA];
  const __bf16* gA1 = gA0 + (size_t)64 * HWP_;
  const __bf16* gB  = &xhi[((size_t)b * HWP_ + kk4) * D_ + d0 + dc0];

  // prologue: stage tile 0 fully
  gld_lds16(gA0, &As[0][ldsoff]);
  gld_lds16(gA1, &As[0][64 * 32 + ldsoff]);
  {
    bf16x4 r0 = *(const bf16x4*)&gB[0];
    bf16x4 r1 = *(const bf16x4*)&gB[D_];
    bf16x4 r2 = *(const bf16x4*)&gB[2 * D_];
    bf16x4 r3 = *(const bf16x4*)&gB[3 * D_];
#pragma unroll
    for (int j = 0; j < 4; j++) {
      bf16x4 o;
      o[0] = r0[j]; o[1] = r1[j]; o[2] = r2[j]; o[3] = r3[j];
      *(bf16x4*)&Bs[0][(dc0 + j) * 40 + kk4] = o;
    }
  }
  __syncthreads();

  int cur = 0;
  for (int k0 = 0; k0 < HWP_; k0 += 32) {
    const bool have = (k0 + 32 < HWP_);
    bf16x4 r0, r1, r2, r3;
    if (have) {
      gld_lds16(gA0 + k0 + 32, &As[cur ^ 1][ldsoff]);
      gld_lds16(gA1 + k0 + 32, &As[cur ^ 1][64 * 32 + ldsoff]);
      const __bf16* src = gB + (size_t)(k0 + 32) * D_;
      r0 = *(const bf16x4*)&src[0];
      r1 = *(const bf16x4*)&src[D_];
      r2 = *(const bf16x4*)&src[2 * D_];
      r3 = *(const bf16x4*)&src[3 * D_];
    }
    bf16x8 af[4], bfr[4];
#pragma unroll
    for (int t = 0; t < 4; t++) {
      int ra = wm + t * 16 + l15;
      int sa = (q ^ ((ra >> 1) & 3)) * 8;
      af[t]  = *(const bf16x8*)&As[cur][ra * 32 + sa];
      bfr[t] = *(const bf16x8*)&Bs[cur][(wn + t * 16 + l15) * 40 + q * 8];
    }
#pragma unroll
    for (int mt = 0; mt < 4; mt++)
#pragma unroll
      for (int nt = 0; nt < 4; nt++)
        acc[mt][nt] = __builtin_amdgcn_mfma_f32_16x16x32_bf16(af[mt], bfr[nt], acc[mt][nt], 0, 0, 0);
    if (have) {
#pragma unroll
      for (int j = 0; j < 4; j++) {
        bf16x4 o;
        o[0] = r0[j]; o[1] = r1[j]; o[2] = r2[j]; o[3] = r3[j];
        *(bf16x4*)&Bs[cur ^ 1][(dc0 + j) * 40 + kk4] = o;
      }
    }
    __syncthreads();
    cur ^= 1;
  }
#pragma unroll
  for (int mt = 0; mt < 4; mt++)
#pragma unroll
    for (int nt = 0; nt < 4; nt++) {
      int d = d0 + wn + nt * 16 + l15;
#pragma unroll
      for (int r = 0; r < 4; r++) {
        int e = e0 + wm + mt * 16 + q * 4 + r;
        g[((size_t)b * E_ + e) * D_ + d] = (__bf16)acc[mt][nt][r];
      }
    }
}

// ---------------- K3: preds = G_flat(64 x 196608) · W2^T, deep-K split MFMA ----------------
// 384 blocks (512 k each, wave handles 128) -> 1.5 blocks/CU vs 0.75 before.
__global__ __launch_bounds__(256) void k3_mfma(const __bf16* __restrict__ g,
                                               const __bf16* __restrict__ w2,
                                               float* __restrict__ out) {
  __shared__ float sp[B_ * C_];
  const int tid = threadIdx.x;
  const int wave = tid >> 6, lane = tid & 63;
  const int q = lane >> 4, l15 = lane & 15;
  const int kbase = blockIdx.x * (K3K_ / K3NB_) + wave * 128;
  f32x4 acc[4] = {};

  for (int i = tid; i < B_ * C_; i += 256) sp[i] = 0.0f;

#pragma unroll
  for (int ks = 0; ks < 4; ks++) {
    int k = kbase + ks * 32 + q * 8;
    bf16x8 bfrag = *(const bf16x8*)&w2[(size_t)l15 * K3K_ + k];
#pragma unroll
    for (int mt = 0; mt < 4; mt++) {
      bf16x8 afrag = *(const bf16x8*)&g[(size_t)(mt * 16 + l15) * K3K_ + k];
      acc[mt] = __builtin_amdgcn_mfma_f32_16x16x32_bf16(afrag, bfrag, acc[mt], 0, 0, 0);
    }
  }
  __syncthreads();
  int c = l15;
  if (c < C_) {
#pragma unroll
    for (int mt = 0; mt < 4; mt++)
#pragma unroll
      for (int r = 0; r < 4; r++) {
        int b = mt * 16 + q * 4 + r;
        atomicAdd(&sp[b * C_ + c], acc[mt][r]);
      }
  }
  __syncthreads();
  const float scale = 1.0f / (196.0f * 256.0f);
  for (int i = tid; i < B_ * C_; i += 256) atomicAdd(&out[i], sp[i] * scale);
}

extern "C" void kernel_launch(void* const* d_in, const int* in_sizes, int n_in,
                              void* d_out, int out_size, void* d_ws, size_t ws_size,
                              hipStream_t stream) {
  const float* x    = (const float*)d_in[0];   // (64,196,768)
  const float* ag_w = (const float*)d_in[1];   // (256,768)
  const float* ag_b = (const float*)d_in[2];   // (256,)
  const float* lm_w = (const float*)d_in[3];   // (2560,768)
  float* out = (float*)d_out;                  // (64,10)

  char* ws = (char*)d_ws;
  const size_t XP_BYTES = (size_t)B_ * HWP_ * D_ * 2;
  const size_t W_BYTES  = (size_t)E_ * D_ * 2;
  const size_t ST_BYTES = (size_t)B_ * E_ * HWP_ * 2;
  const size_t G_BYTES  = (size_t)B_ * E_ * D_ * 2;
  __bf16* xhi = (__bf16*)(ws);
  __bf16* xlo = (__bf16*)(ws + XP_BYTES);
  __bf16* whi = (__bf16*)(ws + 2 * XP_BYTES);
  __bf16* wlo = (__bf16*)(ws + 2 * XP_BYTES + W_BYTES);
  __bf16* st  = (__bf16*)(ws + 2 * XP_BYTES + 2 * W_BYTES);
  __bf16* gb  = (__bf16*)(ws + 2 * XP_BYTES + 2 * W_BYTES + ST_BYTES);
  __bf16* w2  = (__bf16*)(ws + 2 * XP_BYTES + 2 * W_BYTES + ST_BYTES + G_BYTES);

  hipMemsetAsync(d_out, 0, (size_t)out_size * sizeof(float), stream);

  k0_x<<<dim3((B_ * HWP_ * D_) / 4 / 256), dim3(256), 0, stream>>>(x, xhi, xlo);
  k0_prep<<<dim3(192 + (16 * K3K_) / 4 / 256), dim3(256), 0, stream>>>(ag_w, whi, wlo, lm_w, w2);
  k1_signs<<<dim3(MP_ / 128, E_ / 128), dim3(256), 0, stream>>>(xhi, xlo, whi, wlo, ag_b, st);
  k2_g<<<dim3((E_ / 128) * (D_ / 128), B_), dim3(256), 0, stream>>>(st, xhi, gb);
  k3_mfma<<<dim3(K3NB_), dim3(256), 0, stream>>>(gb, w2, out);
}

// Round 4
// 166.188 us; speedup vs baseline: 1.0129x; 1.0129x over previous
//
#include <hip/hip_runtime.h>

#define B_    64
#define HW_   196
#define HWP_  224
#define D_    768
#define E_    256
#define C_    10
#define MP_   (B_*HWP_)   // 14336 padded rows
#define K3K_  (E_*D_)     // 196608 deep-K for final contraction
#define K3NB_ 256         // k3 partial blocks (768 k each) -> non-atomic partials

typedef __bf16 bf16x8 __attribute__((ext_vector_type(8)));
typedef __bf16 bf16x4 __attribute__((ext_vector_type(4)));
typedef float  f32x4  __attribute__((ext_vector_type(4)));

// async global->LDS, 16B per lane; LDS dest is wave-uniform base + lane*16
__device__ __forceinline__ void gld_lds16(const void* g, void* l) {
  __builtin_amdgcn_global_load_lds((const __attribute__((address_space(1))) void*)g,
                                   (__attribute__((address_space(3))) void*)l, 16, 0, 0);
}

// ---------------- K0prep: merged {ag_w -> bf16 hi/lo} and {lm_w -> W2 permute} --------
__global__ __launch_bounds__(256) void k0_prep(const float* __restrict__ w,
                                               __bf16* __restrict__ whi,
                                               __bf16* __restrict__ wlo,
                                               const float* __restrict__ lmw,
                                               __bf16* __restrict__ w2) {
  int bid = blockIdx.x;
  if (bid < 192) {
    size_t i4 = ((size_t)bid * 256 + threadIdx.x) * 4;
    float4 v = *(const float4*)&w[i4];
    float vv[4] = {v.x, v.y, v.z, v.w};
    bf16x4 h, l;
#pragma unroll
    for (int j = 0; j < 4; j++) {
      __bf16 hj = (__bf16)vv[j];
      float r = vv[j] - (float)hj;
      h[j] = hj;
      l[j] = (__bf16)r;
    }
    *(bf16x4*)&whi[i4] = h;
    *(bf16x4*)&wlo[i4] = l;
  } else {
    size_t i4 = ((size_t)(bid - 192) * 256 + threadIdx.x) * 4;  // < 16*K3K_
    int c = (int)(i4 / K3K_);
    int rem = (int)(i4 - (size_t)c * K3K_);
    int e = rem / D_;
    int d = rem - e * D_;
    bf16x4 o;
    if (c < C_) {
      float4 v = *(const float4*)&lmw[((size_t)e * C_ + c) * D_ + d];
      o[0] = (__bf16)v.x; o[1] = (__bf16)v.y; o[2] = (__bf16)v.z; o[3] = (__bf16)v.w;
    } else {
      o[0] = o[1] = o[2] = o[3] = (__bf16)0.0f;
    }
    *(bf16x4*)&w2[i4] = o;
  }
}

// ---------------- K1: sign GEMM, 3-term split-bf16 MFMA, fp32-x direct ----------------
// R3 post-mortem: conflicts=0, occupancy/tile/pipeline changes all neutral -> the
// one un-varied element was the xhi/xlo workspace round-trip. Now A comes straight
// from fp32 x: float4 loads (issued early) -> in-register hi/lo split -> ds_write
// AFTER the MFMA block (T14). B (whi/wlo, L2-resident) stays on gld_lds prefetch.
// k0_x kernel deleted entirely.
__global__ __launch_bounds__(256) void k1_signs(const float* __restrict__ x,
                                                const __bf16* __restrict__ whi,
                                                const __bf16* __restrict__ wlo,
                                                const float* __restrict__ bias,
                                                __bf16* __restrict__ st) {
  __shared__ __align__(16) __bf16 Ah[2][128 * 40];   // stride 40 (16B-aligned rows)
  __shared__ __align__(16) __bf16 Al[2][128 * 40];
  __shared__ __align__(16) __bf16 Bh[2][128 * 32];   // linear (gld_lds dest)
  __shared__ __align__(16) __bf16 Bl[2][128 * 32];
  const int m0 = blockIdx.x * 128;
  const int n0 = blockIdx.y * 128;
  const int tid = threadIdx.x;
  const int wave = tid >> 6, lane = tid & 63;
  const int wm = (wave & 1) * 64, wn = (wave >> 1) * 64;
  const int q = lane >> 4, l15 = lane & 15;

  // A staging: thread -> row ar = tid>>1 (0..127), 16 contiguous k at ac = (tid&1)*16
  const int ar = tid >> 1;
  const int ac = (tid & 1) * 16;
  const int am = m0 + ar;
  const int ab = am / HWP_;
  const int ahp = am - ab * HWP_;
  const bool avalid = (ahp < HW_);
  const float* aptr = &x[((size_t)ab * HW_ + (avalid ? ahp : 0)) * D_ + ac];

  // B staging via gld_lds: wave stages rows [wave*32, +32), two 16-row chunks
  const int br = wave * 32 + (lane >> 2);
  const size_t offB = (size_t)(n0 + br) * D_ + (lane & 3) * 8;
  const size_t brstep = (size_t)16 * D_;
  const int ldB0 = wave * 32 * 32;   // elems
  const int ldB1 = ldB0 + 16 * 32;

  f32x4 acc[4][4] = {};
  float4 a0, a1, a2, a3;

#define K1_LOADA(kk) do { \
    if (avalid) { \
      a0 = *(const float4*)&aptr[(kk)]; \
      a1 = *(const float4*)&aptr[(kk) + 4]; \
      a2 = *(const float4*)&aptr[(kk) + 8]; \
      a3 = *(const float4*)&aptr[(kk) + 12]; \
    } else { \
      a0 = a1 = a2 = a3 = make_float4(0.f, 0.f, 0.f, 0.f); \
    } \
  } while (0)

#define K1_CONVWRITE(buf) do { \
    float va[16] = {a0.x, a0.y, a0.z, a0.w, a1.x, a1.y, a1.z, a1.w, \
                    a2.x, a2.y, a2.z, a2.w, a3.x, a3.y, a3.z, a3.w}; \
    bf16x8 hh0, hh1, ll0, ll1; \
    _Pragma("unroll") \
    for (int j = 0; j < 8; j++) { \
      __bf16 hj = (__bf16)va[j];     float r = va[j] - (float)hj; \
      hh0[j] = hj; ll0[j] = (__bf16)r; \
      __bf16 hk = (__bf16)va[j + 8]; float s = va[j + 8] - (float)hk; \
      hh1[j] = hk; ll1[j] = (__bf16)s; \
    } \
    *(bf16x8*)&Ah[buf][ar * 40 + ac]     = hh0; \
    *(bf16x8*)&Ah[buf][ar * 40 + ac + 8] = hh1; \
    *(bf16x8*)&Al[buf][ar * 40 + ac]     = ll0; \
    *(bf16x8*)&Al[buf][ar * 40 + ac + 8] = ll1; \
  } while (0)

#define K1_STAGEB(buf, kk) do { \
    gld_lds16(&whi[offB + (kk)],          &Bh[buf][ldB0]); \
    gld_lds16(&whi[offB + brstep + (kk)], &Bh[buf][ldB1]); \
    gld_lds16(&wlo[offB + (kk)],          &Bl[buf][ldB0]); \
    gld_lds16(&wlo[offB + brstep + (kk)], &Bl[buf][ldB1]); \
  } while (0)

  // prologue: tile 0
  K1_LOADA(0);
  K1_STAGEB(0, 0);
  K1_CONVWRITE(0);
  __syncthreads();

  int cur = 0;
  for (int k0 = 0; k0 < D_; k0 += 32) {
    const bool have = (k0 + 32 < D_);
    if (have) {
      K1_LOADA(k0 + 32);            // global loads issued early
      K1_STAGEB(cur ^ 1, k0 + 32);  // DMA prefetch
    }
    bf16x8 ah[4], al[4], bh[4], bl[4];
#pragma unroll
    for (int t = 0; t < 4; t++) {
      int ra = (wm + t * 16 + l15) * 40 + q * 8;
      int rb = (wn + t * 16 + l15) * 32 + q * 8;
      ah[t] = *(const bf16x8*)&Ah[cur][ra];
      al[t] = *(const bf16x8*)&Al[cur][ra];
      bh[t] = *(const bf16x8*)&Bh[cur][rb];
      bl[t] = *(const bf16x8*)&Bl[cur][rb];
    }
#pragma unroll
    for (int mt = 0; mt < 4; mt++)
#pragma unroll
      for (int nt = 0; nt < 4; nt++) {
        acc[mt][nt] = __builtin_amdgcn_mfma_f32_16x16x32_bf16(ah[mt], bh[nt], acc[mt][nt], 0, 0, 0);
        acc[mt][nt] = __builtin_amdgcn_mfma_f32_16x16x32_bf16(al[mt], bh[nt], acc[mt][nt], 0, 0, 0);
        acc[mt][nt] = __builtin_amdgcn_mfma_f32_16x16x32_bf16(ah[mt], bl[nt], acc[mt][nt], 0, 0, 0);
      }
    if (have) K1_CONVWRITE(cur ^ 1);   // vmcnt wait lands here, covered by MFMAs
    __syncthreads();
    cur ^= 1;
  }
#undef K1_LOADA
#undef K1_CONVWRITE
#undef K1_STAGEB

#pragma unroll
  for (int mt = 0; mt < 4; mt++)
#pragma unroll
    for (int nt = 0; nt < 4; nt++) {
      int e = n0 + wn + nt * 16 + l15;
      float bv = bias[e];
#pragma unroll
      for (int r = 0; r < 4; r++) {
        int m = m0 + wm + mt * 16 + q * 4 + r;   // C/D: row=quad*4+reg, col=lane&15
        int b = m / HWP_;
        int hp = m - b * HWP_;
        float v = acc[mt][nt][r] + bv;
        __bf16 s = (hp < HW_ && v > 0.0f) ? (__bf16)1.0f : (__bf16)0.0f;
        st[((size_t)b * E_ + e) * HWP_ + hp] = s;
      }
    }
}

// ---------------- K2: per-batch G = S^T · X  (M=256 e, N=768 d, K=224 hp) ----------------
// 2-phase prefetch; A (st) via gld_lds linear; B now reads fp32 x directly and
// converts to bf16 during the transposed reg-stage (issue-early / write-late).
__global__ __launch_bounds__(256) void k2_g(const __bf16* __restrict__ st,
                                            const float* __restrict__ x,
                                            __bf16* __restrict__ g) {
  __shared__ __align__(16) __bf16 As[2][128 * 32];
  __shared__ __align__(16) __bf16 Bs[2][128 * 40];   // Bs[d][k], stride 40
  const int b  = blockIdx.y;
  const int e0 = (blockIdx.x / 6) * 128;
  const int d0 = (blockIdx.x % 6) * 128;
  const int tid = threadIdx.x;
  const int wave = tid >> 6, lane = tid & 63;
  const int wm = (wave & 1) * 64, wn = (wave >> 1) * 64;
  const int q = lane >> 4, l15 = lane & 15;
  const int sr = tid >> 2, sk = (tid & 3) * 8;
  const int ldsoff = wave * 512;
  // Bs staging: thread owns 4k x 4d micro-tile -> 4x ds_write_b64
  const int kk4 = ((tid >> 2) & 7) * 4;                    // k offset 0..28
  const int dgroup = (tid & 3) | (((tid >> 5) & 7) << 2);  // 0..31
  const int dc0 = dgroup * 4;                              // d offset 0..124
  f32x4 acc[4][4] = {};

  const __bf16* gA0 = &st[((size_t)b * E_ + e0 + sr) * HWP_ + sk];
  const __bf16* gA1 = gA0 + (size_t)64 * HWP_;
  const float4 zero4 = make_float4(0.f, 0.f, 0.f, 0.f);
  float4 f0, f1, f2, f3;

#define K2_LOADB(kk) do { \
    int hp0 = (kk) + kk4; \
    const float* bsrc = &x[((size_t)b * HW_ + hp0) * D_ + d0 + dc0]; \
    f0 = (hp0     < HW_) ? *(const float4*)&bsrc[0]      : zero4; \
    f1 = (hp0 + 1 < HW_) ? *(const float4*)&bsrc[D_]     : zero4; \
    f2 = (hp0 + 2 < HW_) ? *(const float4*)&bsrc[2 * D_] : zero4; \
    f3 = (hp0 + 3 < HW_) ? *(const float4*)&bsrc[3 * D_] : zero4; \
  } while (0)

#define K2_WRITEB(buf) do { \
    float rr0[4] = {f0.x, f0.y, f0.z, f0.w}; \
    float rr1[4] = {f1.x, f1.y, f1.z, f1.w}; \
    float rr2[4] = {f2.x, f2.y, f2.z, f2.w}; \
    float rr3[4] = {f3.x, f3.y, f3.z, f3.w}; \
    _Pragma("unroll") \
    for (int j = 0; j < 4; j++) { \
      bf16x4 o; \
      o[0] = (__bf16)rr0[j]; o[1] = (__bf16)rr1[j]; \
      o[2] = (__bf16)rr2[j]; o[3] = (__bf16)rr3[j]; \
      *(bf16x4*)&Bs[buf][(dc0 + j) * 40 + kk4] = o; \
    } \
  } while (0)

  // prologue: stage tile 0 fully
  gld_lds16(gA0, &As[0][ldsoff]);
  gld_lds16(gA1, &As[0][64 * 32 + ldsoff]);
  K2_LOADB(0);
  K2_WRITEB(0);
  __syncthreads();

  int cur = 0;
  for (int k0 = 0; k0 < HWP_; k0 += 32) {
    const bool have = (k0 + 32 < HWP_);
    if (have) {
      gld_lds16(gA0 + k0 + 32, &As[cur ^ 1][ldsoff]);
      gld_lds16(gA1 + k0 + 32, &As[cur ^ 1][64 * 32 + ldsoff]);
      K2_LOADB(k0 + 32);
    }
    bf16x8 af[4], bfr[4];
#pragma unroll
    for (int t = 0; t < 4; t++) {
      af[t]  = *(const bf16x8*)&As[cur][(wm + t * 16 + l15) * 32 + q * 8];
      bfr[t] = *(const bf16x8*)&Bs[cur][(wn + t * 16 + l15) * 40 + q * 8];
    }
#pragma unroll
    for (int mt = 0; mt < 4; mt++)
#pragma unroll
      for (int nt = 0; nt < 4; nt++)
        acc[mt][nt] = __builtin_amdgcn_mfma_f32_16x16x32_bf16(af[mt], bfr[nt], acc[mt][nt], 0, 0, 0);
    if (have) K2_WRITEB(cur ^ 1);
    __syncthreads();
    cur ^= 1;
  }
#undef K2_LOADB
#undef K2_WRITEB

#pragma unroll
  for (int mt = 0; mt < 4; mt++)
#pragma unroll
    for (int nt = 0; nt < 4; nt++) {
      int d = d0 + wn + nt * 16 + l15;
#pragma unroll
      for (int r = 0; r < 4; r++) {
        int e = e0 + wm + mt * 16 + q * 4 + r;
        g[((size_t)b * E_ + e) * D_ + d] = (__bf16)acc[mt][nt][r];
      }
    }
}

// ---------------- K3: partial preds per k-slice (NO global atomics) ----------------
// R3 post-mortem: 384 blocks x atomicAdd to the same 640 floats = 384-deep serial
// chains per address (~10us hidden tail, doubled by R3's 384-block change).
// Now: 256 blocks write non-atomic partials; k4 reduces them.
__global__ __launch_bounds__(256) void k3_mfma(const __bf16* __restrict__ g,
                                               const __bf16* __restrict__ w2,
                                               float* __restrict__ part) {
  __shared__ float sp[B_ * C_];
  const int tid = threadIdx.x;
  const int wave = tid >> 6, lane = tid & 63;
  const int q = lane >> 4, l15 = lane & 15;
  const int kbase = blockIdx.x * (K3K_ / K3NB_) + wave * (K3K_ / K3NB_ / 4);  // 768, 192
  f32x4 acc[4] = {};

  for (int i = tid; i < B_ * C_; i += 256) sp[i] = 0.0f;

#pragma unroll
  for (int ks = 0; ks < 6; ks++) {
    int k = kbase + ks * 32 + q * 8;
    bf16x8 bfrag = *(const bf16x8*)&w2[(size_t)l15 * K3K_ + k];
#pragma unroll
    for (int mt = 0; mt < 4; mt++) {
      bf16x8 afrag = *(const bf16x8*)&g[(size_t)(mt * 16 + l15) * K3K_ + k];
      acc[mt] = __builtin_amdgcn_mfma_f32_16x16x32_bf16(afrag, bfrag, acc[mt], 0, 0, 0);
    }
  }
  __syncthreads();
  if (l15 < C_) {
#pragma unroll
    for (int mt = 0; mt < 4; mt++)
#pragma unroll
      for (int r = 0; r < 4; r++) {
        int b = mt * 16 + q * 4 + r;
        atomicAdd(&sp[b * C_ + l15], acc[mt][r]);   // LDS atomics only
      }
  }
  __syncthreads();
  for (int i = tid; i < B_ * C_; i += 256)
    part[(size_t)blockIdx.x * (B_ * C_) + i] = sp[i];
}

// ---------------- K4: reduce 256 partials -> out (also removes the out memset) ----------
__global__ __launch_bounds__(256) void k4_reduce(const float* __restrict__ part,
                                                 float* __restrict__ out) {
  __shared__ float sp[256];
  const int b = blockIdx.x;
  const int tid = threadIdx.x;
  const int c = tid & 15, g16 = tid >> 4;   // 16 groups x 16 c-slots
  float s = 0.0f;
  if (c < C_) {
#pragma unroll
    for (int j = 0; j < 16; j++)
      s += part[(size_t)(g16 + 16 * j) * (B_ * C_) + b * C_ + c];
  }
  sp[tid] = s;
  __syncthreads();
  if (tid < C_) {
    float t = 0.0f;
#pragma unroll
    for (int j = 0; j < 16; j++) t += sp[j * 16 + tid];
    out[b * C_ + tid] = t * (1.0f / (196.0f * 256.0f));
  }
}

extern "C" void kernel_launch(void* const* d_in, const int* in_sizes, int n_in,
                              void* d_out, int out_size, void* d_ws, size_t ws_size,
                              hipStream_t stream) {
  const float* x    = (const float*)d_in[0];   // (64,196,768)
  const float* ag_w = (const float*)d_in[1];   // (256,768)
  const float* ag_b = (const float*)d_in[2];   // (256,)
  const float* lm_w = (const float*)d_in[3];   // (2560,768)
  float* out = (float*)d_out;                  // (64,10)

  char* ws = (char*)d_ws;
  const size_t W_BYTES  = (size_t)E_ * D_ * 2;
  const size_t ST_BYTES = (size_t)B_ * E_ * HWP_ * 2;
  const size_t G_BYTES  = (size_t)B_ * E_ * D_ * 2;
  const size_t W2_BYTES = (size_t)16 * K3K_ * 2;
  __bf16* whi  = (__bf16*)(ws);
  __bf16* wlo  = (__bf16*)(ws + W_BYTES);
  __bf16* st   = (__bf16*)(ws + 2 * W_BYTES);
  __bf16* gb   = (__bf16*)(ws + 2 * W_BYTES + ST_BYTES);
  __bf16* w2   = (__bf16*)(ws + 2 * W_BYTES + ST_BYTES + G_BYTES);
  float*  part = (float*)(ws + 2 * W_BYTES + ST_BYTES + G_BYTES + W2_BYTES);

  k0_prep<<<dim3(192 + (16 * K3K_) / 4 / 256), dim3(256), 0, stream>>>(ag_w, whi, wlo, lm_w, w2);
  k1_signs<<<dim3(MP_ / 128, E_ / 128), dim3(256), 0, stream>>>(x, whi, wlo, ag_b, st);
  k2_g<<<dim3((E_ / 128) * (D_ / 128), B_), dim3(256), 0, stream>>>(st, x, gb);
  k3_mfma<<<dim3(K3NB_), dim3(256), 0, stream>>>(gb, w2, part);
  k4_reduce<<<dim3(B_), dim3(256), 0, stream>>>(part, out);
}

// Round 5
// 154.384 us; speedup vs baseline: 1.0903x; 1.0765x over previous
//
#include <hip/hip_runtime.h>

#define B_    64
#define HW_   196
#define HWP_  224
#define D_    768
#define E_    256
#define C_    10
#define MP_   (B_*HWP_)   // 14336 padded rows
#define K3K_  (E_*D_)     // 196608 deep-K for final contraction
#define K3NB_ 256         // k3 partial blocks (768 k each) -> non-atomic partials

typedef __bf16 bf16x8 __attribute__((ext_vector_type(8)));
typedef __bf16 bf16x4 __attribute__((ext_vector_type(4)));
typedef __bf16 bf16x2 __attribute__((ext_vector_type(2)));
typedef float  f32x4  __attribute__((ext_vector_type(4)));

// async global->LDS, 16B per lane; LDS dest is wave-uniform base + lane*16
__device__ __forceinline__ void gld_lds16(const void* g, void* l) {
  __builtin_amdgcn_global_load_lds((const __attribute__((address_space(1))) void*)g,
                                   (__attribute__((address_space(3))) void*)l, 16, 0, 0);
}

// ---------------- K0prep: merged {ag_w -> bf16 hi/lo} and {lm_w -> W2 permute} --------
__global__ __launch_bounds__(256) void k0_prep(const float* __restrict__ w,
                                               __bf16* __restrict__ whi,
                                               __bf16* __restrict__ wlo,
                                               const float* __restrict__ lmw,
                                               __bf16* __restrict__ w2) {
  int bid = blockIdx.x;
  if (bid < 192) {
    size_t i4 = ((size_t)bid * 256 + threadIdx.x) * 4;
    float4 v = *(const float4*)&w[i4];
    float vv[4] = {v.x, v.y, v.z, v.w};
    bf16x4 h, l;
#pragma unroll
    for (int j = 0; j < 4; j++) {
      __bf16 hj = (__bf16)vv[j];
      float r = vv[j] - (float)hj;
      h[j] = hj;
      l[j] = (__bf16)r;
    }
    *(bf16x4*)&whi[i4] = h;
    *(bf16x4*)&wlo[i4] = l;
  } else {
    size_t i4 = ((size_t)(bid - 192) * 256 + threadIdx.x) * 4;  // < 16*K3K_
    int c = (int)(i4 / K3K_);
    int rem = (int)(i4 - (size_t)c * K3K_);
    int e = rem / D_;
    int d = rem - e * D_;
    bf16x4 o;
    if (c < C_) {
      float4 v = *(const float4*)&lmw[((size_t)e * C_ + c) * D_ + d];
      o[0] = (__bf16)v.x; o[1] = (__bf16)v.y; o[2] = (__bf16)v.z; o[3] = (__bf16)v.w;
    } else {
      o[0] = o[1] = o[2] = o[3] = (__bf16)0.0f;
    }
    *(bf16x4*)&w2[i4] = o;
  }
}

// ---------------- K1: sign GEMM, FULL-N (256 e) per block, x read ONCE ----------------
// Block = 64 m-rows x 256 e; 4 waves, wave w owns e-slice [w*64, w*64+64).
// A: fp32 x -> in-reg hi/lo split -> ds_write (issue-early/write-late).
// B: whi/wlo (L2-resident) via gld_lds prefetch, all 256 rows per k-step.
// Epilogue: LDS transpose -> coalesced contiguous-hp st writes (was 448B-strided
// 2-byte scatter, 64 transactions per store instruction).
__global__ __launch_bounds__(256) void k1_signs(const float* __restrict__ x,
                                                const __bf16* __restrict__ whi,
                                                const __bf16* __restrict__ wlo,
                                                const float* __restrict__ bias,
                                                __bf16* __restrict__ st) {
  __shared__ __align__(16) char smem[81920];
  __bf16* Ah = (__bf16*)smem;                  // [2][64*32]   8 KB
  __bf16* Al = (__bf16*)(smem + 8192);         // [2][64*32]   8 KB
  __bf16* Bh = (__bf16*)(smem + 16384);        // [2][256*32] 32 KB
  __bf16* Bl = (__bf16*)(smem + 49152);        // [2][256*32] 32 KB
  const int m0 = blockIdx.x * 64;
  const int tid = threadIdx.x;
  const int wave = tid >> 6, lane = tid & 63;
  const int wn = wave * 64;                    // e-offset of this wave
  const int q = lane >> 4, l15 = lane & 15;

  // A staging: thread -> row ar = tid>>2 (0..63), 8 k at ac = (tid&3)*8
  const int ar = tid >> 2;
  const int ac = (tid & 3) * 8;
  const int am = m0 + ar;
  const int ab = am / HWP_;
  const int ahp = am - ab * HWP_;
  const bool avalid = (ahp < HW_);
  const float* aptr = &x[((size_t)ab * HW_ + (avalid ? ahp : 0)) * D_ + ac];

  // B staging: 4 chunks of 64 rows each; thread covers row ar + c*64 at ac
  const size_t offB = (size_t)ar * D_ + ac;
  const int ldB = wave * 512;                  // lane-linear dest within chunk

  f32x4 acc[4][4] = {};
  float4 a0, a1;

#define K1_LOADA(kk) do { \
    if (avalid) { \
      a0 = *(const float4*)&aptr[(kk)]; \
      a1 = *(const float4*)&aptr[(kk) + 4]; \
    } else { \
      a0 = a1 = make_float4(0.f, 0.f, 0.f, 0.f); \
    } \
  } while (0)

#define K1_CONVWRITE(buf) do { \
    float va[8] = {a0.x, a0.y, a0.z, a0.w, a1.x, a1.y, a1.z, a1.w}; \
    bf16x8 hh, ll; \
    _Pragma("unroll") \
    for (int j = 0; j < 8; j++) { \
      __bf16 hj = (__bf16)va[j]; float r = va[j] - (float)hj; \
      hh[j] = hj; ll[j] = (__bf16)r; \
    } \
    *(bf16x8*)&Ah[(buf) * 2048 + ar * 32 + ac] = hh; \
    *(bf16x8*)&Al[(buf) * 2048 + ar * 32 + ac] = ll; \
  } while (0)

#define K1_STAGEB(buf, kk) do { \
    _Pragma("unroll") \
    for (int c = 0; c < 4; c++) { \
      gld_lds16(&whi[offB + (size_t)c * 64 * D_ + (kk)], &Bh[(buf) * 8192 + c * 2048 + ldB]); \
      gld_lds16(&wlo[offB + (size_t)c * 64 * D_ + (kk)], &Bl[(buf) * 8192 + c * 2048 + ldB]); \
    } \
  } while (0)

  // prologue: tile 0
  K1_LOADA(0);
  K1_STAGEB(0, 0);
  K1_CONVWRITE(0);
  __syncthreads();

  int cur = 0;
  for (int k0 = 0; k0 < D_; k0 += 32) {
    const bool have = (k0 + 32 < D_);
    if (have) {
      K1_LOADA(k0 + 32);            // global loads issued early
      K1_STAGEB(cur ^ 1, k0 + 32);  // DMA prefetch
    }
    bf16x8 ah[4], al[4], bh[4], bl[4];
#pragma unroll
    for (int t = 0; t < 4; t++) {
      int ra = cur * 2048 + (t * 16 + l15) * 32 + q * 8;
      int rb = cur * 8192 + (wn + t * 16 + l15) * 32 + q * 8;
      ah[t] = *(const bf16x8*)&Ah[ra];
      al[t] = *(const bf16x8*)&Al[ra];
      bh[t] = *(const bf16x8*)&Bh[rb];
      bl[t] = *(const bf16x8*)&Bl[rb];
    }
#pragma unroll
    for (int mt = 0; mt < 4; mt++)
#pragma unroll
      for (int nt = 0; nt < 4; nt++) {
        acc[mt][nt] = __builtin_amdgcn_mfma_f32_16x16x32_bf16(ah[mt], bh[nt], acc[mt][nt], 0, 0, 0);
        acc[mt][nt] = __builtin_amdgcn_mfma_f32_16x16x32_bf16(al[mt], bh[nt], acc[mt][nt], 0, 0, 0);
        acc[mt][nt] = __builtin_amdgcn_mfma_f32_16x16x32_bf16(ah[mt], bl[nt], acc[mt][nt], 0, 0, 0);
      }
    if (have) K1_CONVWRITE(cur ^ 1);   // vmcnt wait lands here, covered by MFMAs
    __syncthreads();
    cur ^= 1;
  }
#undef K1_LOADA
#undef K1_CONVWRITE
#undef K1_STAGEB

  // ---- epilogue: sign+bias -> LDS transpose Sload[e][m] -> coalesced st writes ----
  __syncthreads();                       // all MFMA-phase LDS reads done; reuse pool
  __bf16* Sload = (__bf16*)smem;         // [256][72] = 36 KB
#pragma unroll
  for (int mt = 0; mt < 4; mt++)
#pragma unroll
    for (int nt = 0; nt < 4; nt++) {
      int e = wn + nt * 16 + l15;
      float bv = bias[e];
      bf16x4 o;
#pragma unroll
      for (int r = 0; r < 4; r++) {
        int m = m0 + mt * 16 + q * 4 + r;   // C/D: row=quad*4+reg, col=lane&15
        int b = m / HWP_;
        int hp = m - b * HWP_;
        float v = acc[mt][nt][r] + bv;
        o[r] = (hp < HW_ && v > 0.0f) ? (__bf16)1.0f : (__bf16)0.0f;
      }
      *(bf16x4*)&Sload[e * 72 + mt * 16 + q * 4] = o;
    }
  __syncthreads();
#pragma unroll
  for (int it = 0; it < 16; it++) {
    int e = (tid >> 4) + it * 16;
    int m4 = (tid & 15) * 4;
    bf16x4 v = *(const bf16x4*)&Sload[e * 72 + m4];
    int mabs = m0 + m4;                  // 4-run never straddles b (224 % 4 == 0)
    int b = mabs / HWP_;
    int hp = mabs - b * HWP_;
    *(bf16x4*)&st[((size_t)b * E_ + e) * HWP_ + hp] = v;
  }
}

// ---------------- K2: per-batch G = S^T · X, FULL-M (256 e) per block --------------
// Block = (d0, b): all 256 e x 128 d, K=224. 512 threads = 8 waves (4e x 2d).
// x[b] d-slice read ONCE (was twice); st[b] (112 KB) L2-hot across its 6 d-blocks.
__global__ __launch_bounds__(512) void k2_g(const __bf16* __restrict__ st,
                                            const float* __restrict__ x,
                                            __bf16* __restrict__ g) {
  __shared__ __align__(16) __bf16 As[2][256 * 32];   // 32 KB
  __shared__ __align__(16) __bf16 Bs[2][128 * 40];   // 20 KB, Bs[d][k] stride 40
  const int b  = blockIdx.y;
  const int d0 = blockIdx.x * 128;
  const int tid = threadIdx.x;
  const int wave = tid >> 6, lane = tid & 63;
  const int WE = (wave & 3) * 64;        // e-offset
  const int WD = (wave >> 2) * 64;       // d-offset within 128
  const int q = lane >> 4, l15 = lane & 15;
  // A staging: thread -> row ar = tid>>2 (0..127), 8 k at ac = (tid&3)*8; rows ar, ar+128
  const int ar = tid >> 2, ac = (tid & 3) * 8;
  const int ldA = wave * 512;
  // B staging: thread owns 2k x 4d: dg = tid&31 (d = 4*dg), kp = tid>>5 (k = 2*kp)
  const int dg = tid & 31, kp = tid >> 5;
  f32x4 acc[4][4] = {};

  const __bf16* gA = &st[((size_t)b * E_ + ar) * HWP_ + ac];
  const float4 zero4 = make_float4(0.f, 0.f, 0.f, 0.f);
  float4 f0, f1;

#define K2_STAGEA(buf, kk) do { \
    gld_lds16(gA + (kk),                       &As[buf][ldA]); \
    gld_lds16(gA + (size_t)128 * HWP_ + (kk),  &As[buf][4096 + ldA]); \
  } while (0)

#define K2_LOADB(kk) do { \
    int hp0 = (kk) + 2 * kp; \
    const float* bsrc = &x[((size_t)b * HW_ + hp0) * D_ + d0 + 4 * dg]; \
    f0 = (hp0     < HW_) ? *(const float4*)&bsrc[0]  : zero4; \
    f1 = (hp0 + 1 < HW_) ? *(const float4*)&bsrc[D_] : zero4; \
  } while (0)

#define K2_WRITEB(buf) do { \
    float rr0[4] = {f0.x, f0.y, f0.z, f0.w}; \
    float rr1[4] = {f1.x, f1.y, f1.z, f1.w}; \
    _Pragma("unroll") \
    for (int j = 0; j < 4; j++) { \
      bf16x2 o; \
      o[0] = (__bf16)rr0[j]; o[1] = (__bf16)rr1[j]; \
      *(bf16x2*)&Bs[buf][(4 * dg + j) * 40 + 2 * kp] = o; \
    } \
  } while (0)

  // prologue: stage tile 0 fully
  K2_STAGEA(0, 0);
  K2_LOADB(0);
  K2_WRITEB(0);
  __syncthreads();

  int cur = 0;
  for (int k0 = 0; k0 < HWP_; k0 += 32) {
    const bool have = (k0 + 32 < HWP_);
    if (have) {
      K2_STAGEA(cur ^ 1, k0 + 32);
      K2_LOADB(k0 + 32);
    }
    bf16x8 af[4], bfr[4];
#pragma unroll
    for (int t = 0; t < 4; t++) {
      af[t]  = *(const bf16x8*)&As[cur][(WE + t * 16 + l15) * 32 + q * 8];
      bfr[t] = *(const bf16x8*)&Bs[cur][(WD + t * 16 + l15) * 40 + q * 8];
    }
#pragma unroll
    for (int mt = 0; mt < 4; mt++)
#pragma unroll
      for (int nt = 0; nt < 4; nt++)
        acc[mt][nt] = __builtin_amdgcn_mfma_f32_16x16x32_bf16(af[mt], bfr[nt], acc[mt][nt], 0, 0, 0);
    if (have) K2_WRITEB(cur ^ 1);
    __syncthreads();
    cur ^= 1;
  }
#undef K2_STAGEA
#undef K2_LOADB
#undef K2_WRITEB

#pragma unroll
  for (int mt = 0; mt < 4; mt++)
#pragma unroll
    for (int nt = 0; nt < 4; nt++) {
      int d = d0 + WD + nt * 16 + l15;
#pragma unroll
      for (int r = 0; r < 4; r++) {
        int e = WE + mt * 16 + q * 4 + r;
        g[((size_t)b * E_ + e) * D_ + d] = (__bf16)acc[mt][nt][r];
      }
    }
}

// ---------------- K3: partial preds per k-slice (NO global atomics) ----------------
__global__ __launch_bounds__(256) void k3_mfma(const __bf16* __restrict__ g,
                                               const __bf16* __restrict__ w2,
                                               float* __restrict__ part) {
  __shared__ float sp[B_ * C_];
  const int tid = threadIdx.x;
  const int wave = tid >> 6, lane = tid & 63;
  const int q = lane >> 4, l15 = lane & 15;
  const int kbase = blockIdx.x * (K3K_ / K3NB_) + wave * (K3K_ / K3NB_ / 4);  // 768, 192
  f32x4 acc[4] = {};

  for (int i = tid; i < B_ * C_; i += 256) sp[i] = 0.0f;

#pragma unroll
  for (int ks = 0; ks < 6; ks++) {
    int k = kbase + ks * 32 + q * 8;
    bf16x8 bfrag = *(const bf16x8*)&w2[(size_t)l15 * K3K_ + k];
#pragma unroll
    for (int mt = 0; mt < 4; mt++) {
      bf16x8 afrag = *(const bf16x8*)&g[(size_t)(mt * 16 + l15) * K3K_ + k];
      acc[mt] = __builtin_amdgcn_mfma_f32_16x16x32_bf16(afrag, bfrag, acc[mt], 0, 0, 0);
    }
  }
  __syncthreads();
  if (l15 < C_) {
#pragma unroll
    for (int mt = 0; mt < 4; mt++)
#pragma unroll
      for (int r = 0; r < 4; r++) {
        int b = mt * 16 + q * 4 + r;
        atomicAdd(&sp[b * C_ + l15], acc[mt][r]);   // LDS atomics only
      }
  }
  __syncthreads();
  for (int i = tid; i < B_ * C_; i += 256)
    part[(size_t)blockIdx.x * (B_ * C_) + i] = sp[i];
}

// ---------------- K4: reduce 256 partials -> out ----------------
__global__ __launch_bounds__(256) void k4_reduce(const float* __restrict__ part,
                                                 float* __restrict__ out) {
  __shared__ float sp[256];
  const int b = blockIdx.x;
  const int tid = threadIdx.x;
  const int c = tid & 15, g16 = tid >> 4;   // 16 groups x 16 c-slots
  float s = 0.0f;
  if (c < C_) {
#pragma unroll
    for (int j = 0; j < 16; j++)
      s += part[(size_t)(g16 + 16 * j) * (B_ * C_) + b * C_ + c];
  }
  sp[tid] = s;
  __syncthreads();
  if (tid < C_) {
    float t = 0.0f;
#pragma unroll
    for (int j = 0; j < 16; j++) t += sp[j * 16 + tid];
    out[b * C_ + tid] = t * (1.0f / (196.0f * 256.0f));
  }
}

extern "C" void kernel_launch(void* const* d_in, const int* in_sizes, int n_in,
                              void* d_out, int out_size, void* d_ws, size_t ws_size,
                              hipStream_t stream) {
  const float* x    = (const float*)d_in[0];   // (64,196,768)
  const float* ag_w = (const float*)d_in[1];   // (256,768)
  const float* ag_b = (const float*)d_in[2];   // (256,)
  const float* lm_w = (const float*)d_in[3];   // (2560,768)
  float* out = (float*)d_out;                  // (64,10)

  char* ws = (char*)d_ws;
  const size_t W_BYTES  = (size_t)E_ * D_ * 2;
  const size_t ST_BYTES = (size_t)B_ * E_ * HWP_ * 2;
  const size_t G_BYTES  = (size_t)B_ * E_ * D_ * 2;
  const size_t W2_BYTES = (size_t)16 * K3K_ * 2;
  __bf16* whi  = (__bf16*)(ws);
  __bf16* wlo  = (__bf16*)(ws + W_BYTES);
  __bf16* st   = (__bf16*)(ws + 2 * W_BYTES);
  __bf16* gb   = (__bf16*)(ws + 2 * W_BYTES + ST_BYTES);
  __bf16* w2   = (__bf16*)(ws + 2 * W_BYTES + ST_BYTES + G_BYTES);
  float*  part = (float*)(ws + 2 * W_BYTES + ST_BYTES + G_BYTES + W2_BYTES);

  k0_prep<<<dim3(192 + (16 * K3K_) / 4 / 256), dim3(256), 0, stream>>>(ag_w, whi, wlo, lm_w, w2);
  k1_signs<<<dim3(MP_ / 64), dim3(256), 0, stream>>>(x, whi, wlo, ag_b, st);
  k2_g<<<dim3(D_ / 128, B_), dim3(512), 0, stream>>>(st, x, gb);
  k3_mfma<<<dim3(K3NB_), dim3(256), 0, stream>>>(gb, w2, part);
  k4_reduce<<<dim3(B_), dim3(256), 0, stream>>>(part, out);
}